// Round 7
// baseline (2061.008 us; speedup 1.0000x reference)
//
#include <hip/hip_runtime.h>
#include <math.h>

typedef float vf4 __attribute__((ext_vector_type(4)));

static constexpr int Ncnt = 32768;
static constexpr int Kcb  = 4096;
static constexpr int Dim  = 256;

static constexpr float EPSf  = 1e-5f;
static constexpr float KEPSf = (float)(4096.0 * 1e-5);

// d_out float offsets (reference return order, flattened)
static constexpr size_t OQ  = 0;
static constexpr size_t OI  = (size_t)Ncnt * Dim;
static constexpr size_t OL  = OI + Ncnt;
static constexpr size_t OE  = OL + 1;
static constexpr size_t OCS = OE + (size_t)Kcb * Dim;
static constexpr size_t OW  = OCS + Kcb;
static constexpr size_t OU  = OW + (size_t)Kcb * Dim;
static constexpr size_t OS  = OU + Kcb;
static constexpr size_t OR  = OS + Kcb;

// ---------------------------------------------------------------------------
// numpy pairwise_sum over fl(p[i]*p[i]) for n=256 (bit-exact np.sum(x*x,1))
__device__ __forceinline__ float np_sq256(const float* __restrict__ p) {
  float tot[2];
  #pragma unroll
  for (int h = 0; h < 2; ++h) {
    const float* a = p + h * 128;
    float r[8];
    #pragma unroll
    for (int j = 0; j < 8; ++j) r[j] = __fmul_rn(a[j], a[j]);
    for (int i = 8; i < 128; i += 8)
      #pragma unroll
      for (int j = 0; j < 8; ++j) r[j] = __fadd_rn(r[j], __fmul_rn(a[i + j], a[i + j]));
    tot[h] = __fadd_rn(__fadd_rn(__fadd_rn(r[0], r[1]), __fadd_rn(r[2], r[3])),
                       __fadd_rn(__fadd_rn(r[4], r[5]), __fadd_rn(r[6], r[7])));
  }
  return __fadd_rn(tot[0], tot[1]);
}

__global__ void rowsq_np(const float* __restrict__ E, float* __restrict__ e2, int rows) {
  const int k = blockIdx.x * 256 + threadIdx.x;
  if (k < rows) e2[k] = np_sq256(E + (size_t)k * Dim);
}

// ---------------------------------------------------------------------------
// tiled transpose: row-major [K][256] -> Et[dq][k][4] (quad-major, codes inner)
__global__ void transpose_cb(const float* __restrict__ E, float* __restrict__ Et) {
  __shared__ float Ts[64][68];
  const int t  = threadIdx.x;
  const int k0 = blockIdx.x * 64;
  const int d0 = blockIdx.y * 64;
  {
    const int c = t >> 2;
    const int q = t & 3;
    #pragma unroll
    for (int i = 0; i < 4; ++i) {
      vf4 v = *(const vf4*)(E + (size_t)(k0 + c) * Dim + d0 + (q + 4 * i) * 4);
      *(vf4*)(&Ts[c][(q + 4 * i) * 4]) = v;
    }
  }
  __syncthreads();
  {
    const int c  = t & 63;
    const int j0 = t >> 6;
    #pragma unroll
    for (int j = 0; j < 4; ++j) {
      const int dql = j0 + 4 * j;
      vf4 v = *(const vf4*)(&Ts[c][dql * 4]);
      *(vf4*)(Et + ((size_t)(d0 / 4 + dql) * Kcb + k0 + c) * 4) = v;
    }
  }
}

// ---------------------------------------------------------------------------
// f32 argmin, numpy-bit-exact: s_k = fl(fl(x2 - fl(2*dot)) + e2[k]), first-idx.
// 64 rows/block (LDS, stride 260), 8 rows x 8 codes per thread, chunk = 256.
// b-ONLY double-buffer (R5 lesson: dbuf of both a and b -> ~230 live VGPRs ->
// scratch spill; b-only peaks ~185). a stays single-buffered (LDS broadcast,
// short latency). launch_bounds(256,2): 2 blocks/CU (LDS-capped), VGPR cap 256.
__global__ __launch_bounds__(256, 2) void argmin_t(
    const float* __restrict__ Et, const float* __restrict__ x2g,
    const float* __restrict__ X, const float* __restrict__ e2,
    int* __restrict__ out_idx)
{
  __shared__ float As[64 * 260];            // 66560 B -> 2 blocks/CU
  const int tid  = threadIdx.x;
  const int tx   = tid & 31;                // code lane (consecutive codes)
  const int ty   = tid >> 5;                // row group (8 rows), 0..7
  const int row0 = blockIdx.x * 64;

  { // stage 64 rows, coalesced reads
    const int r  = tid >> 2;                // 0..63
    const int q0 = tid & 3;
    const vf4* xp = (const vf4*)(X + (size_t)(row0 + r) * Dim);
    #pragma unroll
    for (int i = 0; i < 16; ++i) {
      const int q = q0 + 4 * i;
      vf4 v = xp[q];
      *(vf4*)(As + r * 260 + q * 4) = v;
    }
  }
  __syncthreads();

  float xr[8];
  #pragma unroll
  for (int r = 0; r < 8; ++r) xr[r] = x2g[row0 + ty * 8 + r];

  float m1[8]; int i1[8];
  #pragma unroll
  for (int r = 0; r < 8; ++r) { m1[r] = INFINITY; i1[r] = 0x7fffffff; }

  const float* Abase = As + (ty * 8) * 260;

  for (int kc = 0; kc < Kcb; kc += 256) {
    float acc[8][8];
    #pragma unroll
    for (int r = 0; r < 8; ++r)
      #pragma unroll
      for (int c = 0; c < 8; ++c) acc[r][c] = 0.0f;

    const vf4* Bp = ((const vf4*)Et) + kc + tx;
    vf4 b0[8], b1[8];
    #pragma unroll
    for (int c = 0; c < 8; ++c) b0[c] = Bp[c * 32];

    for (int dq = 0; dq < 64; dq += 2) {
      { // prefetch dq+1 b before the FMA wall on b0
        const vf4* Bn = Bp + Kcb;
        #pragma unroll
        for (int c = 0; c < 8; ++c) b1[c] = Bn[c * 32];
      }
      {
        vf4 a[8];
        #pragma unroll
        for (int r = 0; r < 8; ++r) a[r] = *(const vf4*)(Abase + r * 260 + dq * 4);
        #pragma unroll
        for (int c = 0; c < 8; ++c)
          #pragma unroll
          for (int dd = 0; dd < 4; ++dd)                // serial ascending-d chain
            #pragma unroll
            for (int r = 0; r < 8; ++r)
              acc[r][c] = fmaf(a[r][dd], b0[c][dd], acc[r][c]);
      }
      if (dq + 2 < 64) { // prefetch dq+2 b into b0
        const vf4* B2 = Bp + 2 * (size_t)Kcb;
        #pragma unroll
        for (int c = 0; c < 8; ++c) b0[c] = B2[c * 32];
      }
      {
        vf4 a[8];
        #pragma unroll
        for (int r = 0; r < 8; ++r)
          a[r] = *(const vf4*)(Abase + r * 260 + (dq + 1) * 4);
        #pragma unroll
        for (int c = 0; c < 8; ++c)
          #pragma unroll
          for (int dd = 0; dd < 4; ++dd)
            #pragma unroll
            for (int r = 0; r < 8; ++r)
              acc[r][c] = fmaf(a[r][dd], b1[c][dd], acc[r][c]);
      }
      Bp += 2 * (size_t)Kcb;
    }

    #pragma unroll
    for (int c = 0; c < 8; ++c) {
      const int k = kc + c * 32 + tx;
      const float ee = e2[k];
      #pragma unroll
      for (int r = 0; r < 8; ++r) {
        const float s = __fadd_rn(__fsub_rn(xr[r], __fmul_rn(2.0f, acc[r][c])), ee);
        if (s < m1[r]) { m1[r] = s; i1[r] = k; }        // k ascending within thread
      }
    }
  }

  // cross-thread (tx) reduction per row, lexicographic (value, index)
  __syncthreads();
  float* R1 = As;
  float* RI = As + 2048;
  #pragma unroll
  for (int r = 0; r < 8; ++r) {
    const int row = ty * 8 + r;
    R1[row * 32 + tx] = m1[r];
    RI[row * 32 + tx] = __int_as_float(i1[r]);
  }
  __syncthreads();
  if (tid < 64) {
    float gm = INFINITY; int gi = 0x7fffffff;
    #pragma unroll
    for (int t = 0; t < 32; ++t) {
      const float v1 = R1[tid * 32 + t];
      const int   vi = __float_as_int(RI[tid * 32 + t]);
      if (v1 < gm || (v1 == gm && vi < gi)) { gm = v1; gi = vi; }
    }
    out_idx[row0 + tid] = gi;
  }
}

// ------------------------------- quantized gather + loss + counts + dw atomics
__global__ void quantize_stats(const float* __restrict__ X, const float* __restrict__ E,
                               const int* __restrict__ idx, float* __restrict__ out,
                               float* __restrict__ counts, float* __restrict__ dw,
                               double* __restrict__ loss_acc)
{
  __shared__ double part[4];
  const int tid  = threadIdx.x;
  const int lane = tid & 63, w = tid >> 6;
  const int row  = blockIdx.x * 4 + w;
  const int k    = idx[row];
  const vf4 xv = ((const vf4*)X)[(size_t)row * 64 + lane];
  const vf4 qv = ((const vf4*)E)[(size_t)k * 64 + lane];
  ((vf4*)out)[(size_t)row * 64 + lane] = qv;
  const float d0 = xv[0]-qv[0], d1 = xv[1]-qv[1], d2 = xv[2]-qv[2], d3 = xv[3]-qv[3];
  double ps = (double)(d0*d0 + d1*d1 + d2*d2 + d3*d3);
  #pragma unroll
  for (int o = 32; o; o >>= 1) ps += __shfl_down(ps, o);
  #pragma unroll
  for (int j = 0; j < 4; ++j)
    atomicAdd(dw + (size_t)k * Dim + lane * 4 + j, xv[j]);
  if (lane == 0) {
    part[w] = ps;
    atomicAdd(counts + k, 1.0f);
    out[OI + row] = (float)k;
  }
  __syncthreads();
  if (tid == 0) atomicAdd(loss_acc, part[0] + part[1] + part[2] + part[3]);
}

// ------------------------------------------------- per-code EMA scalar updates
__global__ void cs_usage(const float* __restrict__ ecs, const float* __restrict__ usage,
                         const float* __restrict__ counts, float* __restrict__ out,
                         int* __restrict__ pos_cnt)
{
  __shared__ int si[256];
  const int tid = threadIdx.x;
  const int k   = blockIdx.x * 256 + tid;
  const float cnt = counts[k];
  const float ncs = __fadd_rn(__fmul_rn(ecs[k], 0.99f), __fmul_rn(0.01f, cnt));
  out[OCS + k] = ncs;
  const float nus = __fadd_rn(__fmul_rn(usage[k], 0.99f), __fmul_rn(0.01f, cnt));
  out[OU + k] = nus;
  si[tid] = (nus > 0.0f) ? 1 : 0;
  __syncthreads();
  for (int s = 128; s; s >>= 1) {
    if (tid < s) si[tid] += si[tid + s];
    __syncthreads();
  }
  if (tid == 0) atomicAdd(pos_cnt, si[0]);
}

// n = np.sum(new_cs), numpy pairwise over 4096
__global__ void n_np_kernel(const float* __restrict__ ncs, float* __restrict__ nf) {
  __shared__ float leaf[32];
  const int t = threadIdx.x;
  if (t < 32) {
    const float* a = ncs + t * 128;
    float r[8];
    #pragma unroll
    for (int j = 0; j < 8; ++j) r[j] = a[j];
    for (int i = 8; i < 128; i += 8)
      #pragma unroll
      for (int j = 0; j < 8; ++j) r[j] = __fadd_rn(r[j], a[i + j]);
    leaf[t] = __fadd_rn(__fadd_rn(__fadd_rn(r[0], r[1]), __fadd_rn(r[2], r[3])),
                        __fadd_rn(__fadd_rn(r[4], r[5]), __fadd_rn(r[6], r[7])));
  }
  __syncthreads();
  if (t == 0) {
    float v[32];
    #pragma unroll
    for (int i = 0; i < 32; ++i) v[i] = leaf[i];
    for (int n = 32; n > 1; n >>= 1)
      for (int i = 0; i < (n >> 1); ++i) v[i] = __fadd_rn(v[2 * i], v[2 * i + 1]);
    *nf = v[0];
  }
}

// new_ema_w (in place over dw accum) and pre-embedding, numpy-f32 op order
__global__ void emb_pre(const float* __restrict__ emaw, float* __restrict__ out,
                        const float* __restrict__ nf, float* __restrict__ pre)
{
  const int k = blockIdx.x;
  const int d = threadIdx.x;
  const size_t o = (size_t)k * Dim + d;
  const float dwv = out[OW + o];
  const float w = __fadd_rn(__fmul_rn(emaw[o], 0.99f), __fmul_rn(0.01f, dwv));
  out[OW + o] = w;
  const float nv  = *nf;
  const float ncs = out[OCS + k];
  const float cs  = __fmul_rn(__fdiv_rn(__fadd_rn(ncs, EPSf), __fadd_rn(nv, KEPSf)), nv);
  const float p = __fdiv_rn(w, cs);
  pre[o] = p;
  out[OE + o] = p;
}

__global__ void used_scatter(const int* __restrict__ idx2, int* __restrict__ used) {
  const int i = blockIdx.x * 256 + threadIdx.x;
  used[idx2[i]] = 1;
}

__global__ void finalize_k(const float* __restrict__ X, const int* __restrict__ used,
                           const int* __restrict__ steps_in, const int* __restrict__ rnd,
                           float* __restrict__ out)
{
  const int k = blockIdx.x, d = threadIdx.x;
  const int u = used[k];
  const float st = u ? 0.0f : (float)steps_in[k] + 1.0f;
  const bool dead = st > 100.0f;
  if (dead) out[OE + (size_t)k * Dim + d] = X[(size_t)rnd[k] * Dim + d];
  if (d == 0) out[OS + k] = dead ? 0.0f : st;
}

__global__ void write_scalars(const double* __restrict__ loss_acc,
                              const int* __restrict__ pos_cnt, float* __restrict__ out)
{
  if (threadIdx.x == 0) {
    out[OL] = 0.25f * (float)(*loss_acc / (double)((size_t)Ncnt * Dim));
    out[OR] = (float)(*pos_cnt) / (float)Kcb;
  }
}

// ---------------------------------------------------------------------- launch
extern "C" void kernel_launch(void* const* d_in, const int* in_sizes, int n_in,
                              void* d_out, int out_size, void* d_ws, size_t ws_size,
                              hipStream_t stream)
{
  const float* X     = (const float*)d_in[0];
  const float* E     = (const float*)d_in[1];
  const float* ECS   = (const float*)d_in[2];
  const float* EMAW  = (const float*)d_in[3];
  const float* USAGE = (const float*)d_in[4];
  const int*   STEPS = (const int*)d_in[5];
  const int*   RND   = (const int*)d_in[6];
  float* out = (float*)d_out;

  float* wsf = (float*)d_ws;
  float*  counts   = wsf;                          // [4096]  zeroed
  int*    used     = (int*)(wsf + 4096);           // [4096]  zeroed
  double* loss_acc = (double*)(wsf + 8192);        //         zeroed
  float*  nf       = wsf + 8194;
  int*    pos_cnt  = (int*)(wsf + 8195);
  const size_t ZN  = 8200;                         // zero region, floats
  float* x2g  = wsf + 8320;                        // [32768]
  float* e2   = wsf + 41088;                       // [4096]
  float* e2p  = wsf + 45184;                       // [4096]
  int*   idx1 = (int*)(wsf + 49280);               // [32768]
  int*   idx2 = (int*)(wsf + 82048);               // [32768]
  float* Et   = wsf + 114944;                      // [1048576] transposed codebook
  float* pre  = wsf + 1163520;                     // [1048576]

  hipMemsetAsync(d_ws, 0, ZN * sizeof(float), stream);
  hipMemsetAsync(out + OW, 0, (size_t)Kcb * Dim * sizeof(float), stream); // dw accum

  dim3 tgrid(Kcb / 64, Dim / 64);

  rowsq_np      <<<Ncnt / 256, 256, 0, stream>>>(X, x2g, Ncnt);
  rowsq_np      <<<Kcb / 256,  256, 0, stream>>>(E, e2, Kcb);
  transpose_cb  <<<tgrid,      256, 0, stream>>>(E, Et);
  argmin_t      <<<Ncnt / 64,  256, 0, stream>>>(Et, x2g, X, e2, idx1);
  quantize_stats<<<Ncnt / 4,   256, 0, stream>>>(X, E, idx1, out, counts, out + OW, loss_acc);
  cs_usage      <<<Kcb / 256,  256, 0, stream>>>(ECS, USAGE, counts, out, pos_cnt);
  n_np_kernel   <<<1,          64,  0, stream>>>(out + OCS, nf);
  emb_pre       <<<Kcb,        256, 0, stream>>>(EMAW, out, nf, pre);
  rowsq_np      <<<Kcb / 256,  256, 0, stream>>>(pre, e2p, Kcb);
  transpose_cb  <<<tgrid,      256, 0, stream>>>(pre, Et);
  argmin_t      <<<Ncnt / 64,  256, 0, stream>>>(Et, x2g, X, e2p, idx2);
  used_scatter  <<<Ncnt / 256, 256, 0, stream>>>(idx2, used);
  finalize_k    <<<Kcb,        256, 0, stream>>>(X, used, STEPS, RND, out);
  write_scalars <<<1,          64,  0, stream>>>(loss_acc, pos_cnt, out);

  (void)in_sizes; (void)n_in; (void)out_size; (void)ws_size;
}

// Round 8
// 2006.823 us; speedup vs baseline: 1.0270x; 1.0270x over previous
//
#include <hip/hip_runtime.h>
#include <math.h>

typedef float vf4 __attribute__((ext_vector_type(4)));

static constexpr int Ncnt = 32768;
static constexpr int Kcb  = 4096;
static constexpr int Dim  = 256;

static constexpr float EPSf  = 1e-5f;
static constexpr float KEPSf = (float)(4096.0 * 1e-5);

// d_out float offsets (reference return order, flattened)
static constexpr size_t OQ  = 0;
static constexpr size_t OI  = (size_t)Ncnt * Dim;
static constexpr size_t OL  = OI + Ncnt;
static constexpr size_t OE  = OL + 1;
static constexpr size_t OCS = OE + (size_t)Kcb * Dim;
static constexpr size_t OW  = OCS + Kcb;
static constexpr size_t OU  = OW + (size_t)Kcb * Dim;
static constexpr size_t OS  = OU + Kcb;
static constexpr size_t OR  = OS + Kcb;

// ---------------------------------------------------------------------------
// numpy pairwise_sum over fl(p[i]*p[i]) for n=256 (bit-exact np.sum(x*x,1))
__device__ __forceinline__ float np_sq256(const float* __restrict__ p) {
  float tot[2];
  #pragma unroll
  for (int h = 0; h < 2; ++h) {
    const float* a = p + h * 128;
    float r[8];
    #pragma unroll
    for (int j = 0; j < 8; ++j) r[j] = __fmul_rn(a[j], a[j]);
    for (int i = 8; i < 128; i += 8)
      #pragma unroll
      for (int j = 0; j < 8; ++j) r[j] = __fadd_rn(r[j], __fmul_rn(a[i + j], a[i + j]));
    tot[h] = __fadd_rn(__fadd_rn(__fadd_rn(r[0], r[1]), __fadd_rn(r[2], r[3])),
                       __fadd_rn(__fadd_rn(r[4], r[5]), __fadd_rn(r[6], r[7])));
  }
  return __fadd_rn(tot[0], tot[1]);
}

__global__ void rowsq_np(const float* __restrict__ E, float* __restrict__ e2, int rows) {
  const int k = blockIdx.x * 256 + threadIdx.x;
  if (k < rows) e2[k] = np_sq256(E + (size_t)k * Dim);
}

// ---------------------------------------------------------------------------
// tiled transpose: row-major [K][256] -> Et[dq][k][4] (quad-major, codes inner)
__global__ void transpose_cb(const float* __restrict__ E, float* __restrict__ Et) {
  __shared__ float Ts[64][68];
  const int t  = threadIdx.x;
  const int k0 = blockIdx.x * 64;
  const int d0 = blockIdx.y * 64;
  {
    const int c = t >> 2;
    const int q = t & 3;
    #pragma unroll
    for (int i = 0; i < 4; ++i) {
      vf4 v = *(const vf4*)(E + (size_t)(k0 + c) * Dim + d0 + (q + 4 * i) * 4);
      *(vf4*)(&Ts[c][(q + 4 * i) * 4]) = v;
    }
  }
  __syncthreads();
  {
    const int c  = t & 63;
    const int j0 = t >> 6;
    #pragma unroll
    for (int j = 0; j < 4; ++j) {
      const int dql = j0 + 4 * j;
      vf4 v = *(const vf4*)(&Ts[c][dql * 4]);
      *(vf4*)(Et + ((size_t)(d0 / 4 + dql) * Kcb + k0 + c) * 4) = v;
    }
  }
}

// ---------------------------------------------------------------------------
// f32 argmin, numpy-bit-exact: s_k = fl(fl(x2 - fl(2*dot)) + e2[k]), first-idx.
// 64 rows/block (LDS, stride 260), 8 rows x 8 codes per thread, chunk = 256,
// single-buffered (R5/R7: prefetch regs -> spill or no gain). FMA nest is
// c { r { dd } } so the first FMA quad depends only on a[0]/b[0] -> compiler
// can wait progressively (lgkmcnt(7..0)) instead of draining all 8 ds_reads.
// launch_bounds(256,2): 2 blocks/CU (LDS-capped), VGPR cap 256.
__global__ __launch_bounds__(256, 2) void argmin_t(
    const float* __restrict__ Et, const float* __restrict__ x2g,
    const float* __restrict__ X, const float* __restrict__ e2,
    int* __restrict__ out_idx)
{
  __shared__ float As[64 * 260];            // 66560 B -> 2 blocks/CU
  const int tid  = threadIdx.x;
  const int tx   = tid & 31;                // code lane (consecutive codes)
  const int ty   = tid >> 5;                // row group (8 rows), 0..7
  const int row0 = blockIdx.x * 64;

  { // stage 64 rows, coalesced reads
    const int r  = tid >> 2;                // 0..63
    const int q0 = tid & 3;
    const vf4* xp = (const vf4*)(X + (size_t)(row0 + r) * Dim);
    #pragma unroll
    for (int i = 0; i < 16; ++i) {
      const int q = q0 + 4 * i;
      vf4 v = xp[q];
      *(vf4*)(As + r * 260 + q * 4) = v;
    }
  }
  __syncthreads();

  float xr[8];
  #pragma unroll
  for (int r = 0; r < 8; ++r) xr[r] = x2g[row0 + ty * 8 + r];

  float m1[8]; int i1[8];
  #pragma unroll
  for (int r = 0; r < 8; ++r) { m1[r] = INFINITY; i1[r] = 0x7fffffff; }

  const float* Abase = As + (ty * 8) * 260;

  for (int kc = 0; kc < Kcb; kc += 256) {
    float acc[8][8];
    #pragma unroll
    for (int r = 0; r < 8; ++r)
      #pragma unroll
      for (int c = 0; c < 8; ++c) acc[r][c] = 0.0f;

    const vf4* Bp = ((const vf4*)Et) + kc + tx;
    for (int dq = 0; dq < 64; ++dq) {
      vf4 b[8];
      #pragma unroll
      for (int c = 0; c < 8; ++c) b[c] = Bp[c * 32];    // longest latency first
      vf4 a[8];
      #pragma unroll
      for (int r = 0; r < 8; ++r) a[r] = *(const vf4*)(Abase + r * 260 + dq * 4);
      #pragma unroll
      for (int c = 0; c < 8; ++c)
        #pragma unroll
        for (int r = 0; r < 8; ++r)
          #pragma unroll
          for (int dd = 0; dd < 4; ++dd)                // serial ascending-d chain
            acc[r][c] = fmaf(a[r][dd], b[c][dd], acc[r][c]);
      Bp += Kcb;
    }

    #pragma unroll
    for (int c = 0; c < 8; ++c) {
      const int k = kc + c * 32 + tx;
      const float ee = e2[k];
      #pragma unroll
      for (int r = 0; r < 8; ++r) {
        const float s = __fadd_rn(__fsub_rn(xr[r], __fmul_rn(2.0f, acc[r][c])), ee);
        if (s < m1[r]) { m1[r] = s; i1[r] = k; }        // k ascending within thread
      }
    }
  }

  // cross-thread (tx) reduction per row, lexicographic (value, index)
  __syncthreads();
  float* R1 = As;
  float* RI = As + 2048;
  #pragma unroll
  for (int r = 0; r < 8; ++r) {
    const int row = ty * 8 + r;
    R1[row * 32 + tx] = m1[r];
    RI[row * 32 + tx] = __int_as_float(i1[r]);
  }
  __syncthreads();
  if (tid < 64) {
    float gm = INFINITY; int gi = 0x7fffffff;
    #pragma unroll
    for (int t = 0; t < 32; ++t) {
      const float v1 = R1[tid * 32 + t];
      const int   vi = __float_as_int(RI[tid * 32 + t]);
      if (v1 < gm || (v1 == gm && vi < gi)) { gm = v1; gi = vi; }
    }
    out_idx[row0 + tid] = gi;
  }
}

// ------------------------------- quantized gather + loss + counts + dw atomics
__global__ void quantize_stats(const float* __restrict__ X, const float* __restrict__ E,
                               const int* __restrict__ idx, float* __restrict__ out,
                               float* __restrict__ counts, float* __restrict__ dw,
                               double* __restrict__ loss_acc)
{
  __shared__ double part[4];
  const int tid  = threadIdx.x;
  const int lane = tid & 63, w = tid >> 6;
  const int row  = blockIdx.x * 4 + w;
  const int k    = idx[row];
  const vf4 xv = ((const vf4*)X)[(size_t)row * 64 + lane];
  const vf4 qv = ((const vf4*)E)[(size_t)k * 64 + lane];
  ((vf4*)out)[(size_t)row * 64 + lane] = qv;
  const float d0 = xv[0]-qv[0], d1 = xv[1]-qv[1], d2 = xv[2]-qv[2], d3 = xv[3]-qv[3];
  double ps = (double)(d0*d0 + d1*d1 + d2*d2 + d3*d3);
  #pragma unroll
  for (int o = 32; o; o >>= 1) ps += __shfl_down(ps, o);
  #pragma unroll
  for (int j = 0; j < 4; ++j)
    atomicAdd(dw + (size_t)k * Dim + lane * 4 + j, xv[j]);
  if (lane == 0) {
    part[w] = ps;
    atomicAdd(counts + k, 1.0f);
    out[OI + row] = (float)k;
  }
  __syncthreads();
  if (tid == 0) atomicAdd(loss_acc, part[0] + part[1] + part[2] + part[3]);
}

// ------------------------------------------------- per-code EMA scalar updates
__global__ void cs_usage(const float* __restrict__ ecs, const float* __restrict__ usage,
                         const float* __restrict__ counts, float* __restrict__ out,
                         int* __restrict__ pos_cnt)
{
  __shared__ int si[256];
  const int tid = threadIdx.x;
  const int k   = blockIdx.x * 256 + tid;
  const float cnt = counts[k];
  const float ncs = __fadd_rn(__fmul_rn(ecs[k], 0.99f), __fmul_rn(0.01f, cnt));
  out[OCS + k] = ncs;
  const float nus = __fadd_rn(__fmul_rn(usage[k], 0.99f), __fmul_rn(0.01f, cnt));
  out[OU + k] = nus;
  si[tid] = (nus > 0.0f) ? 1 : 0;
  __syncthreads();
  for (int s = 128; s; s >>= 1) {
    if (tid < s) si[tid] += si[tid + s];
    __syncthreads();
  }
  if (tid == 0) atomicAdd(pos_cnt, si[0]);
}

// n = np.sum(new_cs), numpy pairwise over 4096
__global__ void n_np_kernel(const float* __restrict__ ncs, float* __restrict__ nf) {
  __shared__ float leaf[32];
  const int t = threadIdx.x;
  if (t < 32) {
    const float* a = ncs + t * 128;
    float r[8];
    #pragma unroll
    for (int j = 0; j < 8; ++j) r[j] = a[j];
    for (int i = 8; i < 128; i += 8)
      #pragma unroll
      for (int j = 0; j < 8; ++j) r[j] = __fadd_rn(r[j], a[i + j]);
    leaf[t] = __fadd_rn(__fadd_rn(__fadd_rn(r[0], r[1]), __fadd_rn(r[2], r[3])),
                        __fadd_rn(__fadd_rn(r[4], r[5]), __fadd_rn(r[6], r[7])));
  }
  __syncthreads();
  if (t == 0) {
    float v[32];
    #pragma unroll
    for (int i = 0; i < 32; ++i) v[i] = leaf[i];
    for (int n = 32; n > 1; n >>= 1)
      for (int i = 0; i < (n >> 1); ++i) v[i] = __fadd_rn(v[2 * i], v[2 * i + 1]);
    *nf = v[0];
  }
}

// new_ema_w (in place over dw accum) and pre-embedding, numpy-f32 op order
__global__ void emb_pre(const float* __restrict__ emaw, float* __restrict__ out,
                        const float* __restrict__ nf, float* __restrict__ pre)
{
  const int k = blockIdx.x;
  const int d = threadIdx.x;
  const size_t o = (size_t)k * Dim + d;
  const float dwv = out[OW + o];
  const float w = __fadd_rn(__fmul_rn(emaw[o], 0.99f), __fmul_rn(0.01f, dwv));
  out[OW + o] = w;
  const float nv  = *nf;
  const float ncs = out[OCS + k];
  const float cs  = __fmul_rn(__fdiv_rn(__fadd_rn(ncs, EPSf), __fadd_rn(nv, KEPSf)), nv);
  const float p = __fdiv_rn(w, cs);
  pre[o] = p;
  out[OE + o] = p;
}

__global__ void used_scatter(const int* __restrict__ idx2, int* __restrict__ used) {
  const int i = blockIdx.x * 256 + threadIdx.x;
  used[idx2[i]] = 1;
}

__global__ void finalize_k(const float* __restrict__ X, const int* __restrict__ used,
                           const int* __restrict__ steps_in, const int* __restrict__ rnd,
                           float* __restrict__ out)
{
  const int k = blockIdx.x, d = threadIdx.x;
  const int u = used[k];
  const float st = u ? 0.0f : (float)steps_in[k] + 1.0f;
  const bool dead = st > 100.0f;
  if (dead) out[OE + (size_t)k * Dim + d] = X[(size_t)rnd[k] * Dim + d];
  if (d == 0) out[OS + k] = dead ? 0.0f : st;
}

__global__ void write_scalars(const double* __restrict__ loss_acc,
                              const int* __restrict__ pos_cnt, float* __restrict__ out)
{
  if (threadIdx.x == 0) {
    out[OL] = 0.25f * (float)(*loss_acc / (double)((size_t)Ncnt * Dim));
    out[OR] = (float)(*pos_cnt) / (float)Kcb;
  }
}

// ---------------------------------------------------------------------- launch
extern "C" void kernel_launch(void* const* d_in, const int* in_sizes, int n_in,
                              void* d_out, int out_size, void* d_ws, size_t ws_size,
                              hipStream_t stream)
{
  const float* X     = (const float*)d_in[0];
  const float* E     = (const float*)d_in[1];
  const float* ECS   = (const float*)d_in[2];
  const float* EMAW  = (const float*)d_in[3];
  const float* USAGE = (const float*)d_in[4];
  const int*   STEPS = (const int*)d_in[5];
  const int*   RND   = (const int*)d_in[6];
  float* out = (float*)d_out;

  float* wsf = (float*)d_ws;
  float*  counts   = wsf;                          // [4096]  zeroed
  int*    used     = (int*)(wsf + 4096);           // [4096]  zeroed
  double* loss_acc = (double*)(wsf + 8192);        //         zeroed
  float*  nf       = wsf + 8194;
  int*    pos_cnt  = (int*)(wsf + 8195);
  const size_t ZN  = 8200;                         // zero region, floats
  float* x2g  = wsf + 8320;                        // [32768]
  float* e2   = wsf + 41088;                       // [4096]
  float* e2p  = wsf + 45184;                       // [4096]
  int*   idx1 = (int*)(wsf + 49280);               // [32768]
  int*   idx2 = (int*)(wsf + 82048);               // [32768]
  float* Et   = wsf + 114944;                      // [1048576] transposed codebook
  float* pre  = wsf + 1163520;                     // [1048576]

  hipMemsetAsync(d_ws, 0, ZN * sizeof(float), stream);
  hipMemsetAsync(out + OW, 0, (size_t)Kcb * Dim * sizeof(float), stream); // dw accum

  dim3 tgrid(Kcb / 64, Dim / 64);

  rowsq_np      <<<Ncnt / 256, 256, 0, stream>>>(X, x2g, Ncnt);
  rowsq_np      <<<Kcb / 256,  256, 0, stream>>>(E, e2, Kcb);
  transpose_cb  <<<tgrid,      256, 0, stream>>>(E, Et);
  argmin_t      <<<Ncnt / 64,  256, 0, stream>>>(Et, x2g, X, e2, idx1);
  quantize_stats<<<Ncnt / 4,   256, 0, stream>>>(X, E, idx1, out, counts, out + OW, loss_acc);
  cs_usage      <<<Kcb / 256,  256, 0, stream>>>(ECS, USAGE, counts, out, pos_cnt);
  n_np_kernel   <<<1,          64,  0, stream>>>(out + OCS, nf);
  emb_pre       <<<Kcb,        256, 0, stream>>>(EMAW, out, nf, pre);
  rowsq_np      <<<Kcb / 256,  256, 0, stream>>>(pre, e2p, Kcb);
  transpose_cb  <<<tgrid,      256, 0, stream>>>(pre, Et);
  argmin_t      <<<Ncnt / 64,  256, 0, stream>>>(Et, x2g, X, e2p, idx2);
  used_scatter  <<<Ncnt / 256, 256, 0, stream>>>(idx2, used);
  finalize_k    <<<Kcb,        256, 0, stream>>>(X, used, STEPS, RND, out);
  write_scalars <<<1,          64,  0, stream>>>(loss_acc, pos_cnt, out);

  (void)in_sizes; (void)n_in; (void)out_size; (void)ws_size;
}